// Round 1
// baseline (63.464 us; speedup 1.0000x reference)
//
#include <hip/hip_runtime.h>

typedef __attribute__((ext_vector_type(8))) short short8;
typedef __attribute__((ext_vector_type(4))) float f32x4;

#define NRELROWS 502
#define NB 2048
#define DD 128
#define OUT_HALF (NB * DD)

__device__ __forceinline__ short f2bf(float x) {
    union { float f; unsigned u; } c; c.f = x;
    return (short)((c.u + 0x7FFFu + ((c.u >> 16) & 1u)) >> 16);
}

// Precompute: U[r][d] = sum_f rel[r][f]*W1[d][f]
//             V[r][d] = sum_f rel[r][f]*W1[d][128+f] + b1[d]
//             W2f = W2^T packed in MFMA B-fragment order, bf16
__global__ __launch_bounds__(256) void precompute_kernel(
    const float* __restrict__ rel, const float* __restrict__ W1,
    const float* __restrict__ b1, const float* __restrict__ W2,
    float* __restrict__ U, float* __restrict__ V,
    unsigned short* __restrict__ W2f)
{
    const int bid = blockIdx.x;
    const int tid = threadIdx.x;
    if (bid < NRELROWS) {
        __shared__ float srel[DD];
        if (tid < DD) srel[tid] = rel[bid * DD + tid];
        __syncthreads();
        const int half = tid >> 7;      // 0 -> U, 1 -> V
        const int d = tid & 127;
        const float* wrow = W1 + d * 256 + half * 128;
        float acc = 0.f;
#pragma unroll 8
        for (int f = 0; f < 128; f += 4) {
            float4 wv = *(const float4*)(wrow + f);
            acc += srel[f] * wv.x + srel[f + 1] * wv.y +
                   srel[f + 2] * wv.z + srel[f + 3] * wv.w;
        }
        if (half) {
            V[bid * DD + d] = acc + b1[d];
        } else {
            U[bid * DD + d] = acc;
        }
    } else {
        // B-fragment packing: tile = kt*8+nt; within tile: lane l, slot i
        // B[f][n] with n = nt*16+(l&15), f = kt*32+(l>>4)*8+i, value = W2[n][f]
        const int tile = bid - NRELROWS;   // 0..31
        const int kt = tile >> 3, nt = tile & 7;
#pragma unroll
        for (int e = 0; e < 2; ++e) {
            const int within = tid * 2 + e;          // 0..511
            const int l = within >> 3, i = within & 7;
            const int n = nt * 16 + (l & 15);
            const int f = kt * 32 + (l >> 4) * 8 + i;
            W2f[tile * 512 + within] = (unsigned short)f2bf(W2[n * 128 + f]);
        }
    }
}

// Main: one block per query b. 4 waves; wave w owns attn rows [32w, 32w+32).
__global__ __launch_bounds__(256) void main_kernel(
    const float* __restrict__ ent, const float* __restrict__ rel,
    const float* __restrict__ off, const float* __restrict__ b2,
    const int* __restrict__ anchors, const int* __restrict__ rel0,
    const int* __restrict__ p1t, const int* __restrict__ p1r,
    const float* __restrict__ U, const float* __restrict__ V,
    const unsigned short* __restrict__ W2f, float* __restrict__ out)
{
    const int b = blockIdx.x;
    const int tid = threadIdx.x;
    const int w = tid >> 6;
    const int l = tid & 63;
    const int lg = l >> 4;
    const int l15 = l & 15;

    const int aidx = anchors[b];
    const int r0 = rel0[b];
    const int* p1t_b = p1t + (b << 7);
    const int* p1r_b = p1r + (b << 7);

    // A-fragment row indices: m = w*32 + t*16 + l15
    int relA[2];
    relA[0] = p1r_b[(w << 5) + l15];
    relA[1] = p1r_b[(w << 5) + 16 + l15];

    f32x4 acc[2][8];
#pragma unroll
    for (int t = 0; t < 2; ++t)
#pragma unroll
        for (int n = 0; n < 8; ++n) acc[t][n] = (f32x4)0.f;

    const float* Vrow = V + r0 * DD;

#pragma unroll
    for (int kt = 0; kt < 4; ++kt) {
        const int f0 = kt * 32 + lg * 8;
        const float4 vv0 = *(const float4*)(Vrow + f0);
        const float4 vv1 = *(const float4*)(Vrow + f0 + 4);
        short8 af[2];
#pragma unroll
        for (int t = 0; t < 2; ++t) {
            const float* Urow = U + relA[t] * DD + f0;
            const float4 u0 = *(const float4*)(Urow);
            const float4 u1 = *(const float4*)(Urow + 4);
            af[t][0] = f2bf(fmaxf(u0.x + vv0.x, 0.f));
            af[t][1] = f2bf(fmaxf(u0.y + vv0.y, 0.f));
            af[t][2] = f2bf(fmaxf(u0.z + vv0.z, 0.f));
            af[t][3] = f2bf(fmaxf(u0.w + vv0.w, 0.f));
            af[t][4] = f2bf(fmaxf(u1.x + vv1.x, 0.f));
            af[t][5] = f2bf(fmaxf(u1.y + vv1.y, 0.f));
            af[t][6] = f2bf(fmaxf(u1.z + vv1.z, 0.f));
            af[t][7] = f2bf(fmaxf(u1.w + vv1.w, 0.f));
        }
        const unsigned short* Wk = W2f + (kt << 3) * 512 + (l << 3);
#pragma unroll
        for (int nt = 0; nt < 8; ++nt) {
            const short8 bf = *(const short8*)(Wk + (nt << 9));
            acc[0][nt] = __builtin_amdgcn_mfma_f32_16x16x32_bf16(af[0], bf, acc[0][nt], 0, 0, 0);
            acc[1][nt] = __builtin_amdgcn_mfma_f32_16x16x32_bf16(af[1], bf, acc[1][nt], 0, 0, 0);
        }
    }

    // Epilogue: attn[m][d] = acc + b2[d]; accumulate attn * (h_t - h_a - r_t)
    __shared__ float red[4][DD];
    int tg[2][4], rr[2][4];
#pragma unroll
    for (int t = 0; t < 2; ++t) {
        const int4 t4 = *(const int4*)(p1t_b + (w << 5) + (t << 4) + (lg << 2));
        const int4 r4 = *(const int4*)(p1r_b + (w << 5) + (t << 4) + (lg << 2));
        tg[t][0] = t4.x; tg[t][1] = t4.y; tg[t][2] = t4.z; tg[t][3] = t4.w;
        rr[t][0] = r4.x; rr[t][1] = r4.y; rr[t][2] = r4.z; rr[t][3] = r4.w;
    }
    const float* arow = ent + (size_t)aidx * DD;
#pragma unroll
    for (int nt = 0; nt < 8; ++nt) {
        const int d = (nt << 4) + l15;
        const float had = arow[d];
        const float b2d = b2[d];
        float ps = 0.f;
#pragma unroll
        for (int t = 0; t < 2; ++t) {
#pragma unroll
            for (int r2 = 0; r2 < 4; ++r2) {
                const float at = acc[t][nt][r2] + b2d;
                const float ht = ent[(size_t)tg[t][r2] * DD + d];
                const float rt = rel[rr[t][r2] * DD + d];
                ps += at * (ht - had - rt);
            }
        }
        ps += __shfl_xor(ps, 16);
        ps += __shfl_xor(ps, 32);
        if (lg == 0) red[w][d] = ps;
    }
    __syncthreads();
    if (tid < DD) {
        const int d = tid;
        const float s = red[0][d] + red[1][d] + red[2][d] + red[3][d];
        out[(b << 7) + d] = arow[d] + rel[r0 * DD + d] + s;
        out[OUT_HALF + (b << 7) + d] = off[r0 * DD + d];
    }
}

extern "C" void kernel_launch(void* const* d_in, const int* in_sizes, int n_in,
                              void* d_out, int out_size, void* d_ws, size_t ws_size,
                              hipStream_t stream) {
    const float* ent  = (const float*)d_in[0];
    const float* rel  = (const float*)d_in[1];
    const float* off  = (const float*)d_in[2];
    const float* W1   = (const float*)d_in[3];
    const float* b1   = (const float*)d_in[4];
    const float* W2   = (const float*)d_in[5];
    const float* b2   = (const float*)d_in[6];
    const int* anchors = (const int*)d_in[7];
    const int* rel0    = (const int*)d_in[8];
    const int* p1t     = (const int*)d_in[9];
    const int* p1r     = (const int*)d_in[10];
    float* out = (float*)d_out;

    float* U = (float*)d_ws;                       // 502*128 f32
    float* V = U + NRELROWS * DD;                  // 502*128 f32
    unsigned short* W2f = (unsigned short*)(V + NRELROWS * DD);  // 128*128 bf16

    precompute_kernel<<<NRELROWS + 32, 256, 0, stream>>>(rel, W1, b1, W2, U, V, W2f);
    main_kernel<<<NB, 256, 0, stream>>>(ent, rel, off, b2, anchors, rel0,
                                        p1t, p1r, U, V, W2f, out);
}

// Round 2
// 56.685 us; speedup vs baseline: 1.1196x; 1.1196x over previous
//
#include <hip/hip_runtime.h>

typedef __attribute__((ext_vector_type(8))) short short8;
typedef __attribute__((ext_vector_type(4))) float f32x4;

#define NRELROWS 502
#define NB 2048
#define DD 128
#define OUT_HALF (NB * DD)

__device__ __forceinline__ short f2bf(float x) {
    union { float f; unsigned u; } c; c.f = x;
    return (short)((c.u + 0x7FFFu + ((c.u >> 16) & 1u)) >> 16);
}

// Precompute: U[r][d] = sum_f rel[r][f]*W1[d][f]
//             V[r][d] = sum_f rel[r][f]*W1[d][128+f] + b1[d]
//             W2f = W2^T packed in MFMA B-fragment order, bf16
// 4 rel rows per block for W1 reuse; last 32 blocks do the W2 packing.
__global__ __launch_bounds__(256) void precompute_kernel(
    const float* __restrict__ rel, const float* __restrict__ W1,
    const float* __restrict__ b1, const float* __restrict__ W2,
    float* __restrict__ U, float* __restrict__ V,
    unsigned short* __restrict__ W2f)
{
    const int bid = blockIdx.x;
    const int tid = threadIdx.x;
    if (bid < 126) {
        __shared__ float srel[4][DD];
        const int r0 = bid << 2;
        for (int i = tid; i < 512; i += 256) {
            const int r = i >> 7, c = i & 127;
            const int rr = r0 + r;
            srel[r][c] = (rr < NRELROWS) ? rel[rr * DD + c] : 0.f;
        }
        __syncthreads();
        const int half = tid >> 7;      // 0 -> U, 1 -> V
        const int d = tid & 127;
        const float* wrow = W1 + d * 256 + half * 128;
        float a0 = 0.f, a1 = 0.f, a2 = 0.f, a3 = 0.f;
#pragma unroll 8
        for (int f = 0; f < 128; f += 4) {
            const float4 wv = *(const float4*)(wrow + f);
            a0 += srel[0][f]*wv.x + srel[0][f+1]*wv.y + srel[0][f+2]*wv.z + srel[0][f+3]*wv.w;
            a1 += srel[1][f]*wv.x + srel[1][f+1]*wv.y + srel[1][f+2]*wv.z + srel[1][f+3]*wv.w;
            a2 += srel[2][f]*wv.x + srel[2][f+1]*wv.y + srel[2][f+2]*wv.z + srel[2][f+3]*wv.w;
            a3 += srel[3][f]*wv.x + srel[3][f+1]*wv.y + srel[3][f+2]*wv.z + srel[3][f+3]*wv.w;
        }
        float res[4] = {a0, a1, a2, a3};
        const float bb = half ? b1[d] : 0.f;
#pragma unroll
        for (int r = 0; r < 4; ++r) {
            if (r0 + r < NRELROWS) {
                if (half) V[(r0 + r) * DD + d] = res[r] + bb;
                else      U[(r0 + r) * DD + d] = res[r];
            }
        }
    } else {
        // B-fragment packing: tile = kt*8+nt; within tile: lane l, slot i
        // B[f][n] with n = nt*16+(l&15), f = kt*32+(l>>4)*8+i, value = W2[n][f]
        const int tile = bid - 126;   // 0..31
        const int kt = tile >> 3, nt = tile & 7;
#pragma unroll
        for (int e = 0; e < 2; ++e) {
            const int within = tid * 2 + e;          // 0..511
            const int l = within >> 3, i = within & 7;
            const int n = nt * 16 + (l & 15);
            const int f = kt * 32 + (l >> 4) * 8 + i;
            W2f[tile * 512 + within] = (unsigned short)f2bf(W2[n * 128 + f]);
        }
    }
}

// Main: one block per query b. 4 waves; wave w owns attn rows [32w, 32w+32).
// h_t rows are prefetched into LDS via global_load_lds before the MFMA phase.
__global__ __launch_bounds__(256) void main_kernel(
    const float* __restrict__ ent, const float* __restrict__ rel,
    const float* __restrict__ off, const float* __restrict__ b2,
    const int* __restrict__ anchors, const int* __restrict__ rel0,
    const int* __restrict__ p1t, const int* __restrict__ p1r,
    const float* __restrict__ U, const float* __restrict__ V,
    const unsigned short* __restrict__ W2f, float* __restrict__ out)
{
    __shared__ float ht[4][32][DD];   // 64 KB, also reused as reduction scratch
    const int b = blockIdx.x;
    const int tid = threadIdx.x;
    const int w = tid >> 6;
    const int l = tid & 63;
    const int lg = l >> 4;
    const int l15 = l & 15;
    const int half = l >> 5;          // which of the 2 rows in a 1KB chunk

    const int aidx = anchors[b];
    const int r0 = rel0[b];
    const int* p1t_b = p1t + (b << 7);
    const int* p1r_b = p1r + (b << 7);

    // ---- async prefetch of this wave's 32 h_t rows into ht[w] ----
    int rowi[16];
#pragma unroll
    for (int j = 0; j < 16; ++j)
        rowi[j] = p1t_b[(w << 5) + (j << 1) + half];
#pragma unroll
    for (int j = 0; j < 16; ++j) {
        const float* g = ent + (size_t)rowi[j] * DD + ((l & 31) << 2);
        float* lp = &ht[w][j << 1][0];   // wave-uniform dest; lane writes base + l*16
        __builtin_amdgcn_global_load_lds(
            (const __attribute__((address_space(1))) unsigned int*)g,
            (__attribute__((address_space(3))) unsigned int*)lp, 16, 0, 0);
    }

    // ---- MFMA phase: attn = relu(U[p1_rel] + V[rel_0]) @ W2f ----
    int relA[2];
    relA[0] = p1r_b[(w << 5) + l15];
    relA[1] = p1r_b[(w << 5) + 16 + l15];

    f32x4 acc[2][8];
#pragma unroll
    for (int t = 0; t < 2; ++t)
#pragma unroll
        for (int n = 0; n < 8; ++n) acc[t][n] = (f32x4)0.f;

    const float* Vrow = V + r0 * DD;

#pragma unroll
    for (int kt = 0; kt < 4; ++kt) {
        const int f0 = kt * 32 + lg * 8;
        const float4 vv0 = *(const float4*)(Vrow + f0);
        const float4 vv1 = *(const float4*)(Vrow + f0 + 4);
        short8 af[2];
#pragma unroll
        for (int t = 0; t < 2; ++t) {
            const float* Urow = U + relA[t] * DD + f0;
            const float4 u0 = *(const float4*)(Urow);
            const float4 u1 = *(const float4*)(Urow + 4);
            af[t][0] = f2bf(fmaxf(u0.x + vv0.x, 0.f));
            af[t][1] = f2bf(fmaxf(u0.y + vv0.y, 0.f));
            af[t][2] = f2bf(fmaxf(u0.z + vv0.z, 0.f));
            af[t][3] = f2bf(fmaxf(u0.w + vv0.w, 0.f));
            af[t][4] = f2bf(fmaxf(u1.x + vv1.x, 0.f));
            af[t][5] = f2bf(fmaxf(u1.y + vv1.y, 0.f));
            af[t][6] = f2bf(fmaxf(u1.z + vv1.z, 0.f));
            af[t][7] = f2bf(fmaxf(u1.w + vv1.w, 0.f));
        }
        const unsigned short* Wk = W2f + (kt << 3) * 512 + (l << 3);
#pragma unroll
        for (int nt = 0; nt < 8; ++nt) {
            const short8 bf = *(const short8*)(Wk + (nt << 9));
            acc[0][nt] = __builtin_amdgcn_mfma_f32_16x16x32_bf16(af[0], bf, acc[0][nt], 0, 0, 0);
            acc[1][nt] = __builtin_amdgcn_mfma_f32_16x16x32_bf16(af[1], bf, acc[1][nt], 0, 0, 0);
        }
    }

    // ---- epilogue: sum_k (attn + b2) * (h_t - h_a - r_t) ----
    int rr[2][4];
#pragma unroll
    for (int t = 0; t < 2; ++t) {
        const int4 r4 = *(const int4*)(p1r_b + (w << 5) + (t << 4) + (lg << 2));
        rr[t][0] = r4.x; rr[t][1] = r4.y; rr[t][2] = r4.z; rr[t][3] = r4.w;
    }
    const float* arow = ent + (size_t)aidx * DD;

    asm volatile("s_waitcnt vmcnt(0)" ::: "memory");
    __builtin_amdgcn_sched_barrier(0);

    float ps[8];
#pragma unroll
    for (int nt = 0; nt < 8; ++nt) ps[nt] = 0.f;
#pragma unroll
    for (int nt = 0; nt < 8; ++nt) {
        const int d = (nt << 4) + l15;
        const float had = arow[d];
        const float b2d = b2[d];
#pragma unroll
        for (int t = 0; t < 2; ++t) {
#pragma unroll
            for (int r2 = 0; r2 < 4; ++r2) {
                const float at = acc[t][nt][r2] + b2d;
                const float htv = ht[w][(t << 4) + (lg << 2) + r2][d];
                const float rtv = rel[rr[t][r2] * DD + d];
                ps[nt] += at * (htv - had - rtv);
            }
        }
        ps[nt] += __shfl_xor(ps[nt], 16);
        ps[nt] += __shfl_xor(ps[nt], 32);
    }

    __syncthreads();                  // all waves done reading ht
    float* red = &ht[0][0][0];        // reuse LDS as [4][128] scratch
    if (lg == 0) {
#pragma unroll
        for (int nt = 0; nt < 8; ++nt)
            red[w * DD + (nt << 4) + l15] = ps[nt];
    }
    __syncthreads();
    if (tid < DD) {
        const int d = tid;
        const float s = red[d] + red[DD + d] + red[2 * DD + d] + red[3 * DD + d];
        out[(b << 7) + d] = arow[d] + rel[r0 * DD + d] + s;
        out[OUT_HALF + (b << 7) + d] = off[r0 * DD + d];
    }
}

extern "C" void kernel_launch(void* const* d_in, const int* in_sizes, int n_in,
                              void* d_out, int out_size, void* d_ws, size_t ws_size,
                              hipStream_t stream) {
    const float* ent  = (const float*)d_in[0];
    const float* rel  = (const float*)d_in[1];
    const float* off  = (const float*)d_in[2];
    const float* W1   = (const float*)d_in[3];
    const float* b1   = (const float*)d_in[4];
    const float* W2   = (const float*)d_in[5];
    const float* b2   = (const float*)d_in[6];
    const int* anchors = (const int*)d_in[7];
    const int* rel0    = (const int*)d_in[8];
    const int* p1t     = (const int*)d_in[9];
    const int* p1r     = (const int*)d_in[10];
    float* out = (float*)d_out;

    float* U = (float*)d_ws;                       // 502*128 f32
    float* V = U + NRELROWS * DD;                  // 502*128 f32
    unsigned short* W2f = (unsigned short*)(V + NRELROWS * DD);  // 128*128 bf16

    precompute_kernel<<<126 + 32, 256, 0, stream>>>(rel, W1, b1, W2, U, V, W2f);
    main_kernel<<<NB, 256, 0, stream>>>(ent, rel, off, b2, anchors, rel0,
                                        p1t, p1r, U, V, W2f, out);
}